// Round 2
// baseline (6043.534 us; speedup 1.0000x reference)
//
#include <hip/hip_runtime.h>
#include <hip/hip_bf16.h>

// LiquidRNN on MI355X — round 4.
// u_t = [x_t; h_t] @ Mfull + c  (Mfull = Wb@Wh, exact reassociation),
// d = tanh(u), h += (d-h)/tau.
//
// Decomposition: WG(g,s) = batch-group g (16 batches) x H-slice s (64 cols).
// 32 WGs x 256 threads; each wave owns 16 output cols; its weight slice
// (24 A-fragments = 96 VGPRs) is register-resident for the whole kernel.
//
// h-exchange: SELF-VALIDATING tagged payload over compiler-generated
// agent-scope atomics. Each exchanged dword is {bf16 h | step_tag<<16};
// a dword is valid iff its own hi16 == t. Correctness needs only
// same-address coherence — NO cross-address store->flag ordering (round-2's
// rare-replay race) and NO hand-written sc-bit asm (round-3's suspected
// stale-L1 spin hang). Producer fire-and-forget; consumer polls data.
// Liveness/anti-overwrite is structural: all-to-all consumption per group
// means a wave passing its tag-t check proves every wave finished its
// tag-(t-1) reads; per-slot tags go t-1 -> t+1, so a mismatch is always
// "retry", never corruption. hbuf zeroed in prep => replay-safe.

#define S_   1024
#define D_   256
#define H_   512
#define KT_  768   // D_+H_
#define NKC_ 24    // KT_/32

typedef __attribute__((ext_vector_type(4))) float f32x4;
typedef __attribute__((ext_vector_type(8))) short bf16x8;
typedef unsigned long long u64;

static __device__ __forceinline__ unsigned short f2bf(float f) {
    unsigned int x = __float_as_uint(f);
    return (unsigned short)((x + 0x7fffu + ((x >> 16) & 1u)) >> 16);
}

// ---------------- k_prep: Mfrag (direct fragment order), c, itau, zero hbuf ----
// Mfrag[((nt*NKC+kc)*64+lane)*8+j] = bf16( (Wb@Wh)[kc*32+(lane>>4)*8+j][nt*16+(lane&15)] )
// Thread i computes entry (r = i>>9, n = i&511): wave-uniform Wb row reads,
// coalesced Wh reads, single bf16 scatter-store (distinct ushorts — no race).
__global__ void k_prep(const float* __restrict__ Wb, const float* __restrict__ bb,
                       const float* __restrict__ Wh, const float* __restrict__ bh,
                       const float* __restrict__ tau,
                       unsigned short* __restrict__ Mfrag, float* __restrict__ c,
                       float* __restrict__ itau, unsigned* __restrict__ hz) {
    int i = blockIdx.x * 256 + threadIdx.x;
    if (i < KT_ * H_) {
        int r = i >> 9, n = i & 511;
        float acc = 0.f;
        for (int u = 0; u < 512; ++u)
            acc += Wb[r * 512 + u] * Wh[u * 512 + n];
        int kc   = r >> 5;
        int j    = r & 7;
        int lane = (((r >> 3) & 3) << 4) | (n & 15);
        int nt   = n >> 4;
        Mfrag[((nt * NKC_ + kc) * 64 + lane) * 8 + j] = f2bf(acc);
    } else if (i < KT_ * H_ + 512) {
        int n = i - KT_ * H_;
        float acc = bh[n];
        for (int u = 0; u < 512; ++u)
            acc += bb[u] * Wh[u * 512 + n];
        c[n] = acc;
    } else if (i < KT_ * H_ + 1024) {
        itau[i - KT_ * H_ - 512] = 1.0f / tau[i - KT_ * H_ - 512];
    } else {
        int z = i - KT_ * H_ - 1024;
        if (z < 65536) hz[z] = 0u;   // tag 0 never matches any step tag 1..1024
    }
}

// ---------------- k_rnn2: register-resident weights + tagged LLC exchange ------
// hbuf dword layout within a (g,parity) slot of 8192 dwords (4096 u64):
//   dword[(oct*16 + batch)*8 + (hcol&7)], oct = hcol>>3, batch = b&15,
//   value = bf16(h[batch][hcol]) | (tag<<16).
__global__ __launch_bounds__(256, 1)
void k_rnn2(const float* __restrict__ x, const unsigned short* __restrict__ Mfrag,
            const float* __restrict__ c, const float* __restrict__ itau,
            u64* __restrict__ hb, float* __restrict__ out) {
    const int g    = blockIdx.x >> 3;      // batch group 0..3
    const int s    = blockIdx.x & 7;       // h-slice 0..7
    const int tid  = threadIdx.x;
    const int w    = tid >> 6;             // wave 0..3
    const int lane = tid & 63;
    const int quad = lane >> 4;
    const int m16  = lane & 15;
    const int nt   = s * 4 + w;            // global 16-col tile 0..31
    const int C0   = nt * 16 + quad * 4;   // this lane's 4 output cols
    const int b    = g * 16 + m16;         // this lane's batch (B-operand n)

    // ---- weights: 24 A-fragments, register-resident (96 VGPRs/lane) ----
    const bf16x8* Mf = reinterpret_cast<const bf16x8*>(Mfrag);
    bf16x8 wreg[NKC_];
#pragma unroll
    for (int kc = 0; kc < NKC_; ++kc)
        wreg[kc] = Mf[(nt * NKC_ + kc) * 64 + lane];

    const f32x4 cs = *reinterpret_cast<const f32x4*>(c + C0);
    const f32x4 ts = *reinterpret_cast<const f32x4*>(itau + C0);

    // ---- exchange lane constants (u64 units within a 4096-u64 slot) ----
    const int jsel = quad & 1;
    const int st_u = ((C0 >> 3) * 16 + m16) * 4 + jsel * 2;  // producer: 2 u64
    const int ld_u = lane * 4;                               // consumer: +kc*256

    f32x4 h_old = {0.f, 0.f, 0.f, 0.f};

    for (int t = 0; t < S_; ++t) {
        // ---- x loads + x-part MFMAs: independent of the exchange ----
        const float* xp = x + ((size_t)b * S_ + t) * D_ + quad * 8;
        f32x4 xa[8], xb[8];
#pragma unroll
        for (int kc = 0; kc < 8; ++kc) {
            xa[kc] = *reinterpret_cast<const f32x4*>(xp + kc * 32);
            xb[kc] = *reinterpret_cast<const f32x4*>(xp + kc * 32 + 4);
        }
        f32x4 a0 = {0.f, 0.f, 0.f, 0.f}, a1 = {0.f, 0.f, 0.f, 0.f};
#pragma unroll
        for (int kc = 0; kc < 8; ++kc) {
            bf16x8 xv;
#pragma unroll
            for (int j = 0; j < 4; ++j) {
                xv[j]     = (short)f2bf(xa[kc][j]);
                xv[j + 4] = (short)f2bf(xb[kc][j]);
            }
            if (kc & 1) a1 = __builtin_amdgcn_mfma_f32_16x16x32_bf16(wreg[kc], xv, a1, 0, 0, 0);
            else        a0 = __builtin_amdgcn_mfma_f32_16x16x32_bf16(wreg[kc], xv, a0, 0, 0, 0);
        }

        if (t > 0) {
            u64* hbl = hb + (size_t)(g * 2 + (t & 1)) * 4096;
            u64 hl[16][4];
#pragma unroll
            for (int kc = 0; kc < 16; ++kc) {
#pragma unroll
                for (int q = 0; q < 4; ++q)
                    hl[kc][q] = __hip_atomic_load(hbl + kc * 256 + ld_u + q,
                                                  __ATOMIC_RELAXED, __HIP_MEMORY_SCOPE_AGENT);
            }
            // ---- validate tags; reload until every dword carries tag t ----
            const unsigned T = (unsigned)t << 16;
            for (;;) {
                unsigned bad = 0u;
#pragma unroll
                for (int kc = 0; kc < 16; ++kc) {
#pragma unroll
                    for (int q = 0; q < 4; ++q) {
                        unsigned lo = (unsigned)hl[kc][q];
                        unsigned hi = (unsigned)(hl[kc][q] >> 32);
                        bad |= (lo ^ T) | (hi ^ T);
                    }
                }
                if (!__any((bad & 0xFFFF0000u) != 0u)) break;
#pragma unroll
                for (int kc = 0; kc < 16; ++kc) {
#pragma unroll
                    for (int q = 0; q < 4; ++q)
                        hl[kc][q] = __hip_atomic_load(hbl + kc * 256 + ld_u + q,
                                                      __ATOMIC_RELAXED, __HIP_MEMORY_SCOPE_AGENT);
                }
            }
            // ---- unpack (strip tags) + h-part MFMAs ----
#pragma unroll
            for (int kc = 0; kc < 16; ++kc) {
                union { unsigned wv[4]; bf16x8 v; } hv;
#pragma unroll
                for (int q = 0; q < 4; ++q) {
                    unsigned lo = (unsigned)hl[kc][q];
                    unsigned hi = (unsigned)(hl[kc][q] >> 32);
                    hv.wv[q] = (lo & 0xffffu) | (hi << 16);
                }
                if (kc & 1) a1 = __builtin_amdgcn_mfma_f32_16x16x32_bf16(wreg[8 + kc], hv.v, a1, 0, 0, 0);
                else        a0 = __builtin_amdgcn_mfma_f32_16x16x32_bf16(wreg[8 + kc], hv.v, a0, 0, 0, 0);
            }
        }

        // ---- epilogue: u -> tanh -> liquid Euler update, build tagged dwords --
        f32x4 acc = a0 + a1;
        f32x4 hn;
        unsigned dv[4];
        const unsigned Tn = (unsigned)(t + 1) << 16;
#pragma unroll
        for (int r = 0; r < 4; ++r) {
            float u = acc[r] + cs[r];
            float e = __expf(2.f * u);
            float d = 1.f - 2.f / (e + 1.f);          // tanh(u), robust at +-inf
            hn[r] = h_old[r] + (d - h_old[r]) * ts[r];
            dv[r] = (unsigned)f2bf(hn[r]) | Tn;
        }
        h_old = hn;

        // h_{t+1} -> exchange slot (parity (t+1)&1), fire-and-forget
        u64 p0 = (u64)dv[0] | ((u64)dv[1] << 32);
        u64 p1 = (u64)dv[2] | ((u64)dv[3] << 32);
        u64* hbs = hb + (size_t)(g * 2 + ((t + 1) & 1)) * 4096;
        __hip_atomic_store(hbs + st_u,     p0, __ATOMIC_RELAXED, __HIP_MEMORY_SCOPE_AGENT);
        __hip_atomic_store(hbs + st_u + 1, p1, __ATOMIC_RELAXED, __HIP_MEMORY_SCOPE_AGENT);

        // out[b][t][C0..C0+3] — one dwordx4/lane; off the critical path
        *reinterpret_cast<f32x4*>(out + ((size_t)b * S_ + t) * H_ + C0) = hn;
    }
}

// ---------------- launch --------------------------------------------------------
extern "C" void kernel_launch(void* const* d_in, const int* in_sizes, int n_in,
                              void* d_out, int out_size, void* d_ws, size_t ws_size,
                              hipStream_t stream) {
    const float* x   = (const float*)d_in[0];  // [64,1024,256]
    const float* Wb  = (const float*)d_in[1];
    const float* bb  = (const float*)d_in[2];
    const float* Wh  = (const float*)d_in[3];
    const float* bh  = (const float*)d_in[4];
    const float* tau = (const float*)d_in[5];
    float* out = (float*)d_out;                // [64,1024,512] fp32

    char* ws = (char*)d_ws;
    unsigned short* Mfrag = (unsigned short*)ws;             //   786,432 B
    float*          c     = (float*)(ws + 786432);           //     2,048 B
    float*          it    = (float*)(ws + 788480);           //     2,048 B
    u64*            hbuf  = (u64*)(ws + 790528);             //   262,144 B
    // total ws use: 1,052,672 B

    hipLaunchKernelGGL(k_prep, dim3(1796), dim3(256), 0, stream,
                       Wb, bb, Wh, bh, tau, Mfrag, c, it, (unsigned*)hbuf);
    hipLaunchKernelGGL(k_rnn2, dim3(32), dim3(256), 0, stream,
                       x, Mfrag, c, it, hbuf, out);
}